// Round 5
// baseline (431.495 us; speedup 1.0000x reference)
//
#include <hip/hip_runtime.h>
#include <cstdint>
#include <cstddef>

#define BATCH 256
#define NN 400
#define HH 256
#define TDIM 128
#define HALFD 64
#define OUTD 800
#define W2PAD 264   // W2T row stride (bf16 shorts)
#define Y2S 424     // y2 quarter LDS row stride (shorts)
#define BMW 13      // bitmap u32 words per row

using short8  = __attribute__((ext_vector_type(8))) short;
using short4v = __attribute__((ext_vector_type(4))) short;
using f32x4   = __attribute__((ext_vector_type(4))) float;

__device__ __forceinline__ short f2bf_trunc(float x) {
  union { float f; unsigned int u; } c; c.f = x; return (short)(c.u >> 16);
}
__device__ __forceinline__ short f2bf_rne(float x) {
  union { float f; unsigned int u; } c; c.f = x;
  unsigned int r = c.u + 0x7FFFu + ((c.u >> 16) & 1u);
  return (short)(r >> 16);
}

// ---- K2: tproj[b,h] = temb(times[b]) @ W1[1:,:]
__global__ __launch_bounds__(256) void k_temb(
    const float* __restrict__ times, const float* __restrict__ W1,
    float* __restrict__ tproj) {
  int b = blockIdx.x, t = threadIdx.x;
  __shared__ float te[TDIM];
  if (t < HALFD) {
    float f = expf(-9.210340371976184f * (float)t / (float)(HALFD - 1));
    float arg = times[b] * f;
    te[t] = sinf(arg);
    te[t + HALFD] = cosf(arg);
  }
  __syncthreads();
  float acc = 0.f;
#pragma unroll 8
  for (int k = 0; k < TDIM; ++k) acc += te[k] * W1[(1 + k) * HH + t];
  tproj[b * HH + t] = acc;
}

// ---- K4: W2 -> bf16 transposed padded [256 n][264 k]
__global__ __launch_bounds__(256) void k_w2t(const float* __restrict__ W2,
                                             short* __restrict__ W2Tg) {
  int n = blockIdx.x, k = threadIdx.x;
  W2Tg[n * W2PAD + k] = f2bf_rne(W2[k * HH + n]);
}

// ---- MEGA: one block per graph. adj -> bitmap(LDS) -> pq(LDS) ->
//      4 n-quarters of {GEMM1 (g1 on the fly, y2->LDS), AGG (bitmap-expand
//      MFMA) + relu + pool}. Only global traffic: adj read + pooled write.
__global__ __launch_bounds__(1024) void k_mega(const float* __restrict__ adj,
    const short* __restrict__ W2Tg, const float* __restrict__ W1,
    const float* __restrict__ b1, const float* __restrict__ tproj,
    const float* __restrict__ b2, float* __restrict__ pooled) {
  extern __shared__ char smem[];
  short* w2tq        = (short*)smem;                   // 64*264*2  = 33792
  short* y2q         = (short*)(smem + 33792);         // 64*424*2  = 54272
  unsigned int* bmp  = (unsigned int*)(smem + 88064);  // 400*13*4  = 20800
  float* sd          = (float*)(smem + 108864);        // 400*4
  float* su          = (float*)(smem + 110464);
  float* ppL         = (float*)(smem + 112064);
  float* qqL         = (float*)(smem + 113664);
  float* pool        = (float*)(smem + 115264);        // 16*64*4 = 4096 -> 119360 total

  int t = threadIdx.x;
  int wv = t >> 6, lane = t & 63, l15 = lane & 15, l4 = lane >> 4;
  int bg = blockIdx.x;

  // ---- phase A: adj rows -> bitmap + dis/deg (row scan == col scan: adj symmetric)
  const float* abase = adj + (size_t)bg * NN * NN;
#pragma unroll 5
  for (int r = 0; r < 25; ++r) {
    int row = wv * 25 + r;
    unsigned int b8 = 0;
    int c = 0;
    if (lane < 50) {
      float4 v0 = *(const float4*)(abase + (size_t)row * NN + 8 * lane);
      float4 v1 = *(const float4*)(abase + (size_t)row * NN + 8 * lane + 4);
      b8 = (v0.x != 0.f ? 1u : 0u) | (v0.y != 0.f ? 2u : 0u) |
           (v0.z != 0.f ? 4u : 0u) | (v0.w != 0.f ? 8u : 0u) |
           (v1.x != 0.f ? 16u : 0u) | (v1.y != 0.f ? 32u : 0u) |
           (v1.z != 0.f ? 64u : 0u) | (v1.w != 0.f ? 128u : 0u);
      c = __popc(b8);
      if ((row >> 3) == lane) b8 |= 1u << (row & 7);  // self loop bit
    }
    int cs = c;
#pragma unroll
    for (int s = 32; s; s >>= 1) cs += __shfl_xor(cs, s);
    unsigned int p0 = (unsigned int)__shfl((int)b8, 4 * lane);
    unsigned int p1 = (unsigned int)__shfl((int)b8, 4 * lane + 1);
    unsigned int p2 = (unsigned int)__shfl((int)b8, 4 * lane + 2);
    unsigned int p3 = (unsigned int)__shfl((int)b8, 4 * lane + 3);
    if (lane < BMW) bmp[row * BMW + lane] = p0 | (p1 << 8) | (p2 << 16) | (p3 << 24);
    if (lane == 0) {
      float d = rsqrtf((float)cs + 1.f);
      sd[row] = d;
      su[row] = d * (float)cs;
    }
  }
  __syncthreads();

  // ---- phase B: pp = dis_i*(As@su), qq = dis_i*(As@sd) via ctz-walk
  if (t < NN) {
    float ps = 0.f, qs = 0.f;
#pragma unroll
    for (int w = 0; w < BMW; ++w) {
      unsigned int u = bmp[t * BMW + w];
      int base = w * 32;
      while (u) {
        int j = base + __builtin_ctz(u);
        u &= u - 1;
        ps += su[j]; qs += sd[j];
      }
    }
    float d = sd[t];
    ppL[t] = d * ps;
    qqL[t] = d * qs;
  }
  if (t < 192) {  // zero y2q pad rows m=400..423 (read by AGG k-tail, never written by GEMM)
    int n = t / 3, c2 = t % 3;
    short8 z = {};
    *(short8*)(y2q + n * Y2S + 400 + c2 * 8) = z;
  }
  __syncthreads();

  const float* tpr = tproj + bg * HH;

  for (int q = 0; q < 4; ++q) {
    // ---- stage W2T quarter (64 n-rows) ----
#pragma unroll
    for (int i = 0; i < 3; ++i) {
      int idx = i * 1024 + t;
      if (idx < 2112) {  // 64 rows * 33 short8-chunks
        int n = idx / 33, c2 = idx % 33;
        *(short8*)(w2tq + n * W2PAD + c2 * 8) =
            *(const short8*)(W2Tg + (size_t)(q * 64 + n) * W2PAD + c2 * 8);
      }
    }
    __syncthreads();

    // ---- GEMM1: y2q[n][m] = dis_m * relu-free... = dis_m*(g1 @ W2)[m][q*64+n]
    for (int mt = wv; mt < 25; mt += 16) {
      int arow = mt * 16 + l15;
      float ppv = ppL[arow], qqv = qqL[arow];
      f32x4 acc[4];
#pragma unroll
      for (int f = 0; f < 4; ++f) acc[f] = (f32x4){0.f, 0.f, 0.f, 0.f};
#pragma unroll
      for (int k0 = 0; k0 < 8; ++k0) {
        int kk = k0 * 32 + l4 * 8;
        float4 w1a = *(const float4*)(W1 + kk), w1b = *(const float4*)(W1 + kk + 4);
        float4 b1a = *(const float4*)(b1 + kk), b1b = *(const float4*)(b1 + kk + 4);
        float4 tpa = *(const float4*)(tpr + kk), tpb = *(const float4*)(tpr + kk + 4);
        short8 af;
        af[0] = f2bf_trunc(fmaxf(ppv * w1a.x + qqv * tpa.x + b1a.x, 0.f));
        af[1] = f2bf_trunc(fmaxf(ppv * w1a.y + qqv * tpa.y + b1a.y, 0.f));
        af[2] = f2bf_trunc(fmaxf(ppv * w1a.z + qqv * tpa.z + b1a.z, 0.f));
        af[3] = f2bf_trunc(fmaxf(ppv * w1a.w + qqv * tpa.w + b1a.w, 0.f));
        af[4] = f2bf_trunc(fmaxf(ppv * w1b.x + qqv * tpb.x + b1b.x, 0.f));
        af[5] = f2bf_trunc(fmaxf(ppv * w1b.y + qqv * tpb.y + b1b.y, 0.f));
        af[6] = f2bf_trunc(fmaxf(ppv * w1b.z + qqv * tpb.z + b1b.z, 0.f));
        af[7] = f2bf_trunc(fmaxf(ppv * w1b.w + qqv * tpb.w + b1b.w, 0.f));
#pragma unroll
        for (int f = 0; f < 4; ++f) {
          short8 bf = *(const short8*)(w2tq + (f * 16 + l15) * W2PAD + kk);
          acc[f] = __builtin_amdgcn_mfma_f32_16x16x32_bf16(af, bf, acc[f], 0, 0, 0);
        }
      }
      // write y2q (transposed, dis-scaled): n = f*16+l15, m = mt*16 + l4*4 + rr
      float4 d4 = *(const float4*)(sd + mt * 16 + l4 * 4);
#pragma unroll
      for (int f = 0; f < 4; ++f) {
        short4v pk;
        pk[0] = f2bf_trunc(d4.x * acc[f][0]);
        pk[1] = f2bf_trunc(d4.y * acc[f][1]);
        pk[2] = f2bf_trunc(d4.z * acc[f][2]);
        pk[3] = f2bf_trunc(d4.w * acc[f][3]);
        *(short4v*)(y2q + (f * 16 + l15) * Y2S + mt * 16 + l4 * 4) = pk;
      }
    }
    __syncthreads();

    // ---- AGG: C = As @ y2q^T via bitmap-expanded A-frags; relu+pool fused
    {
      int mt0 = wv, mt1 = wv + 16;
      f32x4 accA[4], accB[4];
#pragma unroll
      for (int f = 0; f < 4; ++f) {
        accA[f] = (f32x4){0.f, 0.f, 0.f, 0.f};
        accB[f] = (f32x4){0.f, 0.f, 0.f, 0.f};
      }
#pragma unroll
      for (int ks = 0; ks < 13; ++ks) {
        short8 bfv[4];
#pragma unroll
        for (int f = 0; f < 4; ++f)
          bfv[f] = *(const short8*)(y2q + (f * 16 + l15) * Y2S + ks * 32 + l4 * 8);
        {
          unsigned int bw = bmp[(mt0 * 16 + l15) * BMW + ks] >> (l4 * 8);
          short8 af;
#pragma unroll
          for (int e = 0; e < 8; ++e) af[e] = ((bw >> e) & 1u) ? (short)0x3F80 : (short)0;
#pragma unroll
          for (int f = 0; f < 4; ++f)
            accA[f] = __builtin_amdgcn_mfma_f32_16x16x32_bf16(af, bfv[f], accA[f], 0, 0, 0);
        }
        if (mt1 < 25) {
          unsigned int bw = bmp[(mt1 * 16 + l15) * BMW + ks] >> (l4 * 8);
          short8 af;
#pragma unroll
          for (int e = 0; e < 8; ++e) af[e] = ((bw >> e) & 1u) ? (short)0x3F80 : (short)0;
#pragma unroll
          for (int f = 0; f < 4; ++f)
            accB[f] = __builtin_amdgcn_mfma_f32_16x16x32_bf16(af, bfv[f], accB[f], 0, 0, 0);
        }
      }
      // epilogue: s(n) = sum_m relu(dis_m * C[m][n] + b2[n])
      float4 d4a = *(const float4*)(sd + mt0 * 16 + l4 * 4);
      float4 d4b = (mt1 < 25) ? *(const float4*)(sd + mt1 * 16 + l4 * 4)
                              : (float4){0.f, 0.f, 0.f, 0.f};
#pragma unroll
      for (int f = 0; f < 4; ++f) {
        float b2v = b2[q * 64 + f * 16 + l15];
        float s = fmaxf(d4a.x * accA[f][0] + b2v, 0.f)
                + fmaxf(d4a.y * accA[f][1] + b2v, 0.f)
                + fmaxf(d4a.z * accA[f][2] + b2v, 0.f)
                + fmaxf(d4a.w * accA[f][3] + b2v, 0.f);
        if (mt1 < 25)
          s += fmaxf(d4b.x * accB[f][0] + b2v, 0.f)
             + fmaxf(d4b.y * accB[f][1] + b2v, 0.f)
             + fmaxf(d4b.z * accB[f][2] + b2v, 0.f)
             + fmaxf(d4b.w * accB[f][3] + b2v, 0.f);
        s += __shfl_xor(s, 16);
        s += __shfl_xor(s, 32);
        if (l4 == 0) pool[wv * 64 + f * 16 + l15] = s;
      }
    }
    __syncthreads();
    if (t < 64) {
      float sum = 0.f;
#pragma unroll
      for (int w16 = 0; w16 < 16; ++w16) sum += pool[w16 * 64 + t];
      pooled[(size_t)bg * HH + q * 64 + t] = sum;
    }
    // next stage's w2tq overwrite is >=1 barrier away from GEMM's last read;
    // AGG(q+1) pool writes are 2 barriers away from this reduce. Safe.
  }
}

// ---- K7: logits = (pooled/400) @ Wlin + blin
__global__ __launch_bounds__(256) void k_out(
    const float* __restrict__ pooled, const float* __restrict__ Wlin,
    const float* __restrict__ blin, float* __restrict__ out) {
  int b = blockIdx.x, t = threadIdx.x;
  __shared__ float ps[HH];
  ps[t] = pooled[(size_t)b * HH + t] * (1.f / 400.f);
  __syncthreads();
#pragma unroll
  for (int c = 0; c < 4; ++c) {
    int o = t + c * 256;
    if (o < OUTD) {
      float acc = blin[o];
#pragma unroll 8
      for (int h = 0; h < HH; ++h) acc += ps[h] * Wlin[h * OUTD + o];
      out[b * OUTD + o] = acc;
    }
  }
}

extern "C" void kernel_launch(void* const* d_in, const int* in_sizes, int n_in,
                              void* d_out, int out_size, void* d_ws, size_t ws_size,
                              hipStream_t stream) {
  const float* adj   = (const float*)d_in[0];
  const float* times = (const float*)d_in[1];
  const float* W1    = (const float*)d_in[2];
  const float* b1    = (const float*)d_in[3];
  const float* W2    = (const float*)d_in[4];
  const float* b2    = (const float*)d_in[5];
  const float* Wlin  = (const float*)d_in[6];
  const float* blin  = (const float*)d_in[7];
  float* out = (float*)d_out;

  char* ws = (char*)d_ws;
  size_t off = 0;
  auto alloc = [&](size_t bytes) -> void* {
    void* ptr = ws + off;
    off = (off + bytes + 255) & ~(size_t)255;
    return ptr;
  };
  float* tproj  = (float*)alloc((size_t)BATCH * HH * 4);
  float* pooled = (float*)alloc((size_t)BATCH * HH * 4);
  short* W2Tg   = (short*)alloc((size_t)HH * W2PAD * 2);

  k_temb<<<BATCH, 256, 0, stream>>>(times, W1, tproj);
  k_w2t<<<HH, 256, 0, stream>>>(W2, W2Tg);
  k_mega<<<BATCH, 1024, 119360, stream>>>(adj, W2Tg, W1, b1, tproj, b2, pooled);
  k_out<<<BATCH, 256, 0, stream>>>(pooled, Wlin, blin, out);
}

// Round 6
// 234.111 us; speedup vs baseline: 1.8431x; 1.8431x over previous
//
#include <hip/hip_runtime.h>
#include <cstdint>
#include <cstddef>

#define BATCH 256
#define NN 400
#define HH 256
#define TDIM 128
#define HALFD 64
#define OUTD 800
#define BITW 16     // u32 words per bitmap row (13 used)
#define BMW 13
#define W2PAD 264   // W2T row stride (shorts): 2-way LDS banks (free)
#define Y2S 424     // y2 quarter LDS row stride (shorts): 2-way banks
#define ASBS 36     // As-tile LDS row stride (shorts): 18-bank stride, conflict-free

using short8  = __attribute__((ext_vector_type(8))) short;
using short4v = __attribute__((ext_vector_type(4))) short;
using f32x4   = __attribute__((ext_vector_type(4))) float;

__device__ __forceinline__ short f2bf_trunc(float x) {
  union { float f; unsigned int u; } c; c.f = x; return (short)(c.u >> 16);
}
__device__ __forceinline__ short f2bf_rne(float x) {
  union { float f; unsigned int u; } c; c.f = x;
  unsigned int r = c.u + 0x7FFFu + ((c.u >> 16) & 1u);
  return (short)(r >> 16);
}

// ---- K1: adj -> bitmap [256][400][16 u32] (binary + self loop), dis, dd.
//      Grid (256, 25), 4 waves x 4 rows; lane l covers cols 8l..8l+7.
//      LDS=0, tiny VGPR -> many blocks/CU -> HBM-saturating stream.
__global__ __launch_bounds__(256) void k_prep(const float* __restrict__ adj,
    unsigned int* __restrict__ bits, float* __restrict__ dis,
    float* __restrict__ dd) {
  int bg = blockIdx.x;
  int rbase = blockIdx.y * 16;
  int wv = threadIdx.x >> 6, lane = threadIdx.x & 63;
#pragma unroll
  for (int rr = 0; rr < 4; ++rr) {
    int i = rbase + wv * 4 + rr;
    const float* arow = adj + ((size_t)bg * NN + i) * NN;
    unsigned int b8 = 0; int c = 0;
    if (lane < 50) {
      float4 v0 = *(const float4*)(arow + 8 * lane);
      float4 v1 = *(const float4*)(arow + 8 * lane + 4);
      b8 = (v0.x != 0.f ? 1u : 0u) | (v0.y != 0.f ? 2u : 0u) |
           (v0.z != 0.f ? 4u : 0u) | (v0.w != 0.f ? 8u : 0u) |
           (v1.x != 0.f ? 16u : 0u) | (v1.y != 0.f ? 32u : 0u) |
           (v1.z != 0.f ? 64u : 0u) | (v1.w != 0.f ? 128u : 0u);
      c = __popc(b8);
      if ((i >> 3) == lane) b8 |= 1u << (i & 7);  // self loop
    }
    int cs = c;
#pragma unroll
    for (int s = 32; s; s >>= 1) cs += __shfl_xor(cs, s);
    unsigned int p0 = (unsigned int)__shfl((int)b8, 4 * lane);
    unsigned int p1 = (unsigned int)__shfl((int)b8, 4 * lane + 1);
    unsigned int p2 = (unsigned int)__shfl((int)b8, 4 * lane + 2);
    unsigned int p3 = (unsigned int)__shfl((int)b8, 4 * lane + 3);
    if (lane < BITW)
      bits[((size_t)bg * NN + i) * BITW + lane] =
          (lane < BMW) ? (p0 | (p1 << 8) | (p2 << 16) | (p3 << 24)) : 0u;
    if (lane == 0) {
      float d = rsqrtf((float)cs + 1.f);
      dis[bg * NN + i] = d;
      dd[bg * NN + i] = d * (float)cs;
    }
  }
}

// ---- K2: tproj[b,h] = temb(times[b]) @ W1[1:,:]
__global__ __launch_bounds__(256) void k_temb(
    const float* __restrict__ times, const float* __restrict__ W1,
    float* __restrict__ tproj) {
  int b = blockIdx.x, t = threadIdx.x;
  __shared__ float te[TDIM];
  if (t < HALFD) {
    float f = expf(-9.210340371976184f * (float)t / (float)(HALFD - 1));
    float arg = times[b] * f;
    te[t] = sinf(arg);
    te[t + HALFD] = cosf(arg);
  }
  __syncthreads();
  float acc = 0.f;
#pragma unroll 8
  for (int k = 0; k < TDIM; ++k) acc += te[k] * W1[(1 + k) * HH + t];
  tproj[b * HH + t] = acc;
}

// ---- K3: W2 -> bf16 transposed padded [256 n][264 k]
__global__ __launch_bounds__(256) void k_w2t(const float* __restrict__ W2,
                                             short* __restrict__ W2Tg) {
  int n = blockIdx.x, k = threadIdx.x;
  W2Tg[n * W2PAD + k] = f2bf_rne(W2[k * HH + n]);
}

// ---- K4: fused per-(graph, n-quarter): pq -> GEMM1(y2 quarter in LDS) ->
//      AGG (bitmap->LDS As-tile dbuf, MFMA) -> relu -> pool. 512 thr, 8 waves.
__global__ __launch_bounds__(512, 2) void k_fused(
    const unsigned int* __restrict__ bits, const float* __restrict__ disg,
    const float* __restrict__ ddg, const short* __restrict__ W2Tg,
    const float* __restrict__ W1, const float* __restrict__ b1,
    const float* __restrict__ tproj, const float* __restrict__ b2,
    float* __restrict__ pooled) {
  extern __shared__ char smem[];
  short* w2tq = (short*)smem;                // 64*264*2  = 33792
  short* y2q  = (short*)(smem + 33792);      // 64*424*2  = 54272 -> 88064
  short* asb  = (short*)(smem + 88064);      // 2*400*36*2 = 57600 -> 145664
  float* sd   = (float*)(smem + 145664);
  float* su   = (float*)(smem + 147264);
  float* ppL  = (float*)(smem + 148864);
  float* qqL  = (float*)(smem + 150464);
  float* pool = (float*)(smem + 152064);     // 8*64*4 = 2048 -> 154112 total

  int t = threadIdx.x;
  int wv = t >> 6, lane = t & 63, l15 = lane & 15, l4 = lane >> 4;
  int bg = blockIdx.x, q = blockIdx.y;

  // stage W2T quarter (issue first; overlaps bitmap loads)
#pragma unroll
  for (int i = 0; i < 5; ++i) {
    int idx = i * 512 + t;
    if (idx < 2112) {  // 64 rows * 33 short8 chunks
      int n = idx / 33, c = idx % 33;
      *(short8*)(w2tq + n * W2PAD + c * 8) =
          *(const short8*)(W2Tg + (size_t)(q * 64 + n) * W2PAD + c * 8);
    }
  }

  // bitmap row -> 13 VGPRs; sd/su
  unsigned int w[13];
  if (t < NN) {
    const uint4* bp = (const uint4*)(bits + ((size_t)bg * NN + t) * BITW);
    uint4 qa = bp[0], qb = bp[1], qc = bp[2];
    w[0] = qa.x; w[1] = qa.y; w[2] = qa.z; w[3] = qa.w;
    w[4] = qb.x; w[5] = qb.y; w[6] = qb.z; w[7] = qb.w;
    w[8] = qc.x; w[9] = qc.y; w[10] = qc.z; w[11] = qc.w;
    w[12] = ((const unsigned int*)bp)[12];
    sd[t] = disg[bg * NN + t];
    su[t] = ddg[bg * NN + t];
  } else {
#pragma unroll
    for (int i = 0; i < 13; ++i) w[i] = 0u;
  }
  // zero y2q pad cols m=400..423
  if (t < 192) {
    int n = t / 3, c = t % 3;
    short8 z = {};
    *(short8*)(y2q + n * Y2S + 400 + c * 8) = z;
  }
  __syncthreads();

  // pq: pp = dis_i*(As@su), qq = dis_i*(As@sd) via ctz walk
  if (t < NN) {
    float ps = 0.f, qs = 0.f;
#pragma unroll
    for (int wi = 0; wi < BMW; ++wi) {
      unsigned int u = w[wi];
      int base = wi * 32;
      while (u) {
        int j = base + __builtin_ctz(u);
        u &= u - 1;
        ps += su[j]; qs += sd[j];
      }
    }
    float d = sd[t];
    ppL[t] = d * ps;
    qqL[t] = d * qs;
  }
  __syncthreads();

  // ---- GEMM1: y2q[n][m] = dis_m * (g1 @ W2)[m][q*64+n]
  const float* tpr = tproj + bg * HH;
  for (int mt = wv; mt < 25; mt += 8) {
    int arow = mt * 16 + l15;
    float ppv = ppL[arow], qqv = qqL[arow];
    f32x4 acc[4];
#pragma unroll
    for (int f = 0; f < 4; ++f) acc[f] = (f32x4){0.f, 0.f, 0.f, 0.f};
#pragma unroll
    for (int k0 = 0; k0 < 8; ++k0) {
      int kk = k0 * 32 + l4 * 8;
      float4 w1a = *(const float4*)(W1 + kk), w1b = *(const float4*)(W1 + kk + 4);
      float4 b1a = *(const float4*)(b1 + kk), b1b = *(const float4*)(b1 + kk + 4);
      float4 tpa = *(const float4*)(tpr + kk), tpb = *(const float4*)(tpr + kk + 4);
      short8 af;
      af[0] = f2bf_trunc(fmaxf(ppv * w1a.x + qqv * tpa.x + b1a.x, 0.f));
      af[1] = f2bf_trunc(fmaxf(ppv * w1a.y + qqv * tpa.y + b1a.y, 0.f));
      af[2] = f2bf_trunc(fmaxf(ppv * w1a.z + qqv * tpa.z + b1a.z, 0.f));
      af[3] = f2bf_trunc(fmaxf(ppv * w1a.w + qqv * tpa.w + b1a.w, 0.f));
      af[4] = f2bf_trunc(fmaxf(ppv * w1b.x + qqv * tpb.x + b1b.x, 0.f));
      af[5] = f2bf_trunc(fmaxf(ppv * w1b.y + qqv * tpb.y + b1b.y, 0.f));
      af[6] = f2bf_trunc(fmaxf(ppv * w1b.z + qqv * tpb.z + b1b.z, 0.f));
      af[7] = f2bf_trunc(fmaxf(ppv * w1b.w + qqv * tpb.w + b1b.w, 0.f));
#pragma unroll
      for (int f = 0; f < 4; ++f) {
        short8 bf = *(const short8*)(w2tq + (f * 16 + l15) * W2PAD + kk);
        acc[f] = __builtin_amdgcn_mfma_f32_16x16x32_bf16(af, bf, acc[f], 0, 0, 0);
      }
    }
    float4 d4 = *(const float4*)(sd + mt * 16 + l4 * 4);
#pragma unroll
    for (int f = 0; f < 4; ++f) {
      short4v pk;
      pk[0] = f2bf_trunc(d4.x * acc[f][0]);
      pk[1] = f2bf_trunc(d4.y * acc[f][1]);
      pk[2] = f2bf_trunc(d4.z * acc[f][2]);
      pk[3] = f2bf_trunc(d4.w * acc[f][3]);
      *(short4v*)(y2q + (f * 16 + l15) * Y2S + mt * 16 + l4 * 4) = pk;
    }
  }

  // ---- AGG: C[m][n] = sum_k As[m][k] * y2q[n][k]; As expanded to LDS per K-step
#define EXPAND(BUF, KS)                                                     \
  do {                                                                      \
    if (t < NN) {                                                           \
      unsigned int wd = w[KS];                                              \
      _Pragma("unroll") for (int c = 0; c < 4; ++c) {                       \
        short8 e;                                                           \
        _Pragma("unroll") for (int bb = 0; bb < 8; ++bb)                    \
            e[bb] = ((wd >> (c * 8 + bb)) & 1u) ? (short)0x3F80 : (short)0; \
        *(short8*)(asb + (BUF) * (400 * ASBS) + t * ASBS + c * 8) = e;      \
      }                                                                     \
    }                                                                       \
  } while (0)

  f32x4 acc[4][4];
#pragma unroll
  for (int mi = 0; mi < 4; ++mi)
#pragma unroll
    for (int f = 0; f < 4; ++f) acc[mi][f] = (f32x4){0.f, 0.f, 0.f, 0.f};

  EXPAND(0, 0);
  __syncthreads();  // also covers y2q writes from GEMM1

#pragma unroll
  for (int ks = 0; ks < 13; ++ks) {
    int cur = ks & 1;
    if (ks < 12) EXPAND(cur ^ 1, ks + 1);
    short8 bfv[4];
#pragma unroll
    for (int f = 0; f < 4; ++f)
      bfv[f] = *(const short8*)(y2q + (f * 16 + l15) * Y2S + ks * 32 + l4 * 8);
#pragma unroll
    for (int mi = 0; mi < 4; ++mi) {
      int mt = wv + mi * 8;
      if (mt < 25) {
        short8 af = *(const short8*)(asb + cur * (400 * ASBS) +
                                     (mt * 16 + l15) * ASBS + l4 * 8);
#pragma unroll
        for (int f = 0; f < 4; ++f)
          acc[mi][f] = __builtin_amdgcn_mfma_f32_16x16x32_bf16(af, bfv[f], acc[mi][f], 0, 0, 0);
      }
    }
    __syncthreads();
  }
#undef EXPAND

  // epilogue: s(n) = sum_m relu(dis_m * C[m][n] + b2[n]); pool across waves
#pragma unroll
  for (int f = 0; f < 4; ++f) {
    float b2v = b2[q * 64 + f * 16 + l15];
    float s = 0.f;
#pragma unroll
    for (int mi = 0; mi < 4; ++mi) {
      int mt = wv + mi * 8;
      if (mt < 25) {
        float4 d4 = *(const float4*)(sd + mt * 16 + l4 * 4);
        s += fmaxf(d4.x * acc[mi][f][0] + b2v, 0.f)
           + fmaxf(d4.y * acc[mi][f][1] + b2v, 0.f)
           + fmaxf(d4.z * acc[mi][f][2] + b2v, 0.f)
           + fmaxf(d4.w * acc[mi][f][3] + b2v, 0.f);
      }
    }
    s += __shfl_xor(s, 16);
    s += __shfl_xor(s, 32);
    if (l4 == 0) pool[wv * 64 + f * 16 + l15] = s;
  }
  __syncthreads();
  if (t < 64) {
    float sum = 0.f;
#pragma unroll
    for (int w8 = 0; w8 < 8; ++w8) sum += pool[w8 * 64 + t];
    pooled[(size_t)bg * HH + q * 64 + t] = sum;
  }
}

// ---- K5: logits = (pooled/400) @ Wlin + blin
__global__ __launch_bounds__(256) void k_out(
    const float* __restrict__ pooled, const float* __restrict__ Wlin,
    const float* __restrict__ blin, float* __restrict__ out) {
  int b = blockIdx.x, t = threadIdx.x;
  __shared__ float ps[HH];
  ps[t] = pooled[(size_t)b * HH + t] * (1.f / 400.f);
  __syncthreads();
#pragma unroll
  for (int c = 0; c < 4; ++c) {
    int o = t + c * 256;
    if (o < OUTD) {
      float acc = blin[o];
#pragma unroll 8
      for (int h = 0; h < HH; ++h) acc += ps[h] * Wlin[h * OUTD + o];
      out[b * OUTD + o] = acc;
    }
  }
}

extern "C" void kernel_launch(void* const* d_in, const int* in_sizes, int n_in,
                              void* d_out, int out_size, void* d_ws, size_t ws_size,
                              hipStream_t stream) {
  const float* adj   = (const float*)d_in[0];
  const float* times = (const float*)d_in[1];
  const float* W1    = (const float*)d_in[2];
  const float* b1    = (const float*)d_in[3];
  const float* W2    = (const float*)d_in[4];
  const float* b2    = (const float*)d_in[5];
  const float* Wlin  = (const float*)d_in[6];
  const float* blin  = (const float*)d_in[7];
  float* out = (float*)d_out;

  char* ws = (char*)d_ws;
  size_t off = 0;
  auto alloc = [&](size_t bytes) -> void* {
    void* ptr = ws + off;
    off = (off + bytes + 255) & ~(size_t)255;
    return ptr;
  };
  float* dis    = (float*)alloc((size_t)BATCH * NN * 4);
  float* dd     = (float*)alloc((size_t)BATCH * NN * 4);
  float* tproj  = (float*)alloc((size_t)BATCH * HH * 4);
  float* pooled = (float*)alloc((size_t)BATCH * HH * 4);
  short* W2Tg   = (short*)alloc((size_t)HH * W2PAD * 2);
  unsigned int* bits = (unsigned int*)alloc((size_t)BATCH * NN * BITW * 4);

  k_temb<<<BATCH, 256, 0, stream>>>(times, W1, tproj);
  k_w2t<<<HH, 256, 0, stream>>>(W2, W2Tg);
  k_prep<<<dim3(BATCH, 25), 256, 0, stream>>>(adj, bits, dis, dd);
  k_fused<<<dim3(BATCH, 4), 512, 154112, stream>>>(
      bits, dis, dd, W2Tg, W1, b1, tproj, b2, pooled);
  k_out<<<BATCH, 256, 0, stream>>>(pooled, Wlin, blin, out);
}

// Round 7
// 161.263 us; speedup vs baseline: 2.6757x; 1.4517x over previous
//
#include <hip/hip_runtime.h>
#include <cstdint>
#include <cstddef>

#define BATCH 256
#define NN 400
#define HH 256
#define TDIM 128
#define HALFD 64
#define OUTD 800
#define BITW 16     // u32 words per bitmap row in global (13 used)
#define BMW 13
#define W2PAD 264   // W2T row stride (shorts)
#define Y2S 416     // y2 quarter LDS row stride (shorts)

using short8  = __attribute__((ext_vector_type(8))) short;
using short4v = __attribute__((ext_vector_type(4))) short;
using f32x4   = __attribute__((ext_vector_type(4))) float;

__device__ __forceinline__ short f2bf_trunc(float x) {
  union { float f; unsigned int u; } c; c.f = x; return (short)(c.u >> 16);
}
__device__ __forceinline__ short f2bf_rne(float x) {
  union { float f; unsigned int u; } c; c.f = x;
  unsigned int r = c.u + 0x7FFFu + ((c.u >> 16) & 1u);
  return (short)(r >> 16);
}

// ---- K1: adj -> bitmap [256][400][16 u32] (binary + self loop), dis, dd.
__global__ __launch_bounds__(256) void k_prep(const float* __restrict__ adj,
    unsigned int* __restrict__ bits, float* __restrict__ dis,
    float* __restrict__ dd) {
  int bg = blockIdx.x;
  int rbase = blockIdx.y * 16;
  int wv = threadIdx.x >> 6, lane = threadIdx.x & 63;
#pragma unroll
  for (int rr = 0; rr < 4; ++rr) {
    int i = rbase + wv * 4 + rr;
    const float* arow = adj + ((size_t)bg * NN + i) * NN;
    unsigned int b8 = 0; int c = 0;
    if (lane < 50) {
      float4 v0 = *(const float4*)(arow + 8 * lane);
      float4 v1 = *(const float4*)(arow + 8 * lane + 4);
      b8 = (v0.x != 0.f ? 1u : 0u) | (v0.y != 0.f ? 2u : 0u) |
           (v0.z != 0.f ? 4u : 0u) | (v0.w != 0.f ? 8u : 0u) |
           (v1.x != 0.f ? 16u : 0u) | (v1.y != 0.f ? 32u : 0u) |
           (v1.z != 0.f ? 64u : 0u) | (v1.w != 0.f ? 128u : 0u);
      c = __popc(b8);
      if ((i >> 3) == lane) b8 |= 1u << (i & 7);  // self loop
    }
    int cs = c;
#pragma unroll
    for (int s = 32; s; s >>= 1) cs += __shfl_xor(cs, s);
    unsigned int p0 = (unsigned int)__shfl((int)b8, 4 * lane);
    unsigned int p1 = (unsigned int)__shfl((int)b8, 4 * lane + 1);
    unsigned int p2 = (unsigned int)__shfl((int)b8, 4 * lane + 2);
    unsigned int p3 = (unsigned int)__shfl((int)b8, 4 * lane + 3);
    if (lane < BITW)
      bits[((size_t)bg * NN + i) * BITW + lane] =
          (lane < BMW) ? (p0 | (p1 << 8) | (p2 << 16) | (p3 << 24)) : 0u;
    if (lane == 0) {
      float d = rsqrtf((float)cs + 1.f);
      dis[bg * NN + i] = d;
      dd[bg * NN + i] = d * (float)cs;
    }
  }
}

// ---- K2: tproj[b,h] = temb(times[b]) @ W1[1:,:]
__global__ __launch_bounds__(256) void k_temb(
    const float* __restrict__ times, const float* __restrict__ W1,
    float* __restrict__ tproj) {
  int b = blockIdx.x, t = threadIdx.x;
  __shared__ float te[TDIM];
  if (t < HALFD) {
    float f = expf(-9.210340371976184f * (float)t / (float)(HALFD - 1));
    float arg = times[b] * f;
    te[t] = sinf(arg);
    te[t + HALFD] = cosf(arg);
  }
  __syncthreads();
  float acc = 0.f;
#pragma unroll 8
  for (int k = 0; k < TDIM; ++k) acc += te[k] * W1[(1 + k) * HH + t];
  tproj[b * HH + t] = acc;
}

// ---- K3: W2 -> bf16 transposed padded [256 n][264 k]
__global__ __launch_bounds__(256) void k_w2t(const float* __restrict__ W2,
                                             short* __restrict__ W2Tg) {
  int n = blockIdx.x, k = threadIdx.x;
  W2Tg[n * W2PAD + k] = f2bf_rne(W2[k * HH + n]);
}

// ---- K4: pp = dis_i*(As@dd), qq = dis_i*(As@dis) via bitmap ctz-walk.
__global__ __launch_bounds__(512) void k_pq(const unsigned int* __restrict__ bits,
    const float* __restrict__ dis, const float* __restrict__ dd,
    float* __restrict__ pp, float* __restrict__ qq) {
  int bg = blockIdx.x, t = threadIdx.x;
  __shared__ float sd[NN], su[NN];
  for (int j = t; j < NN; j += 512) { sd[j] = dis[bg * NN + j]; su[j] = dd[bg * NN + j]; }
  __syncthreads();
  if (t >= NN) return;
  const uint4* bp = (const uint4*)(bits + ((size_t)bg * NN + t) * BITW);
  uint4 qa = bp[0], qb = bp[1], qc = bp[2];
  unsigned int wr[13] = {qa.x, qa.y, qa.z, qa.w, qb.x, qb.y, qb.z, qb.w,
                         qc.x, qc.y, qc.z, qc.w, ((const unsigned int*)bp)[12]};
  float ps = 0.f, qs = 0.f;
#pragma unroll
  for (int w = 0; w < BMW; ++w) {
    unsigned int u = wr[w];
    int base = w * 32;
    while (u) {
      int j = base + __builtin_ctz(u);
      u &= u - 1;
      ps += su[j]; qs += sd[j];
    }
  }
  float d = sd[t];
  pp[bg * NN + t] = d * ps;
  qq[bg * NN + t] = d * qs;
}

// ---- K5: fused per-(graph, n-quarter): GEMM1(y2 quarter in LDS) ->
//      AGG (register-expanded bitmap A-frags, barrier-free K-loop) ->
//      relu -> pool. 512 thr, 8 waves, 3 barriers total.
__global__ __launch_bounds__(512, 2) void k_fused(
    const unsigned int* __restrict__ bits, const float* __restrict__ disg,
    const float* __restrict__ ppg, const float* __restrict__ qqg,
    const short* __restrict__ W2Tg, const float* __restrict__ W1,
    const float* __restrict__ b1, const float* __restrict__ tproj,
    const float* __restrict__ b2, float* __restrict__ pooled) {
  extern __shared__ char smem[];
  short* w2tq        = (short*)smem;                    // 64*264*2 = 33792
  short* y2q         = (short*)(smem + 33792);          // 64*416*2 = 53248 -> 87040
  unsigned int* bmpL = (unsigned int*)(smem + 87040);   // 400*13*4 = 20800 -> 107840
  float* sd          = (float*)(smem + 107840);         // 1600 -> 109440
  float* ppL         = (float*)(smem + 109440);         // 1600 -> 111040
  float* qqL         = (float*)(smem + 111040);         // 1600 -> 112640
  float* pool        = (float*)(smem + 112640);         // 8*64*4 = 2048 -> 114688

  int t = threadIdx.x;
  int wv = t >> 6, lane = t & 63, l15 = lane & 15, l4 = lane >> 4;
  int bg = blockIdx.x, q = blockIdx.y;

  // ---- stage: W2T quarter, bitmap, dis/pp/qq, zero y2q pad (m=400..415)
#pragma unroll
  for (int i = 0; i < 5; ++i) {
    int idx = i * 512 + t;
    if (idx < 2112) {  // 64 rows * 33 short8 chunks
      int n = idx / 33, c = idx % 33;
      *(short8*)(w2tq + n * W2PAD + c * 8) =
          *(const short8*)(W2Tg + (size_t)(q * 64 + n) * W2PAD + c * 8);
    }
  }
  if (t < NN) {
    const uint4* bp = (const uint4*)(bits + ((size_t)bg * NN + t) * BITW);
    uint4 qa = bp[0], qb = bp[1], qc = bp[2];
    bmpL[t * BMW + 0] = qa.x;  bmpL[t * BMW + 1] = qa.y;
    bmpL[t * BMW + 2] = qa.z;  bmpL[t * BMW + 3] = qa.w;
    bmpL[t * BMW + 4] = qb.x;  bmpL[t * BMW + 5] = qb.y;
    bmpL[t * BMW + 6] = qb.z;  bmpL[t * BMW + 7] = qb.w;
    bmpL[t * BMW + 8] = qc.x;  bmpL[t * BMW + 9] = qc.y;
    bmpL[t * BMW + 10] = qc.z; bmpL[t * BMW + 11] = qc.w;
    bmpL[t * BMW + 12] = ((const unsigned int*)bp)[12];
    sd[t] = disg[bg * NN + t];
    ppL[t] = ppg[bg * NN + t];
    qqL[t] = qqg[bg * NN + t];
  }
  if (t < 128) {  // zero y2q pad cols m=400..415 for all 64 n-rows
    int n = t >> 1, c = t & 1;
    short8 z = {};
    *(short8*)(y2q + n * Y2S + 400 + c * 8) = z;
  }
  __syncthreads();

  // ---- GEMM1: y2q[n][m] = dis_m * (g1 @ W2)[m][q*64+n]; k0 outer, mt inner
  const float* tpr = tproj + bg * HH;
  float pv[4], qv[4];
#pragma unroll
  for (int mi = 0; mi < 4; ++mi) {
    int mt = wv + mi * 8;
    int arow = mt * 16 + l15;
    pv[mi] = (mt < 25) ? ppL[arow] : 0.f;
    qv[mi] = (mt < 25) ? qqL[arow] : 0.f;
  }
  f32x4 acc[4][4];
#pragma unroll
  for (int mi = 0; mi < 4; ++mi)
#pragma unroll
    for (int f = 0; f < 4; ++f) acc[mi][f] = (f32x4){0.f, 0.f, 0.f, 0.f};

#pragma unroll
  for (int k0 = 0; k0 < 8; ++k0) {
    int kk = k0 * 32 + l4 * 8;
    float4 w1a = *(const float4*)(W1 + kk), w1b = *(const float4*)(W1 + kk + 4);
    float4 b1a = *(const float4*)(b1 + kk), b1b = *(const float4*)(b1 + kk + 4);
    float4 tpa = *(const float4*)(tpr + kk), tpb = *(const float4*)(tpr + kk + 4);
    short8 bf[4];
#pragma unroll
    for (int f = 0; f < 4; ++f)
      bf[f] = *(const short8*)(w2tq + (f * 16 + l15) * W2PAD + kk);
#pragma unroll
    for (int mi = 0; mi < 4; ++mi) {
      if (wv + mi * 8 < 25) {
        float ppv = pv[mi], qqv = qv[mi];
        short8 af;
        af[0] = f2bf_trunc(fmaxf(ppv * w1a.x + qqv * tpa.x + b1a.x, 0.f));
        af[1] = f2bf_trunc(fmaxf(ppv * w1a.y + qqv * tpa.y + b1a.y, 0.f));
        af[2] = f2bf_trunc(fmaxf(ppv * w1a.z + qqv * tpa.z + b1a.z, 0.f));
        af[3] = f2bf_trunc(fmaxf(ppv * w1a.w + qqv * tpa.w + b1a.w, 0.f));
        af[4] = f2bf_trunc(fmaxf(ppv * w1b.x + qqv * tpb.x + b1b.x, 0.f));
        af[5] = f2bf_trunc(fmaxf(ppv * w1b.y + qqv * tpb.y + b1b.y, 0.f));
        af[6] = f2bf_trunc(fmaxf(ppv * w1b.z + qqv * tpb.z + b1b.z, 0.f));
        af[7] = f2bf_trunc(fmaxf(ppv * w1b.w + qqv * tpb.w + b1b.w, 0.f));
#pragma unroll
        for (int f = 0; f < 4; ++f)
          acc[mi][f] = __builtin_amdgcn_mfma_f32_16x16x32_bf16(af, bf[f], acc[mi][f], 0, 0, 0);
      }
    }
  }
  // write y2q (transposed, dis-scaled): n = f*16+l15, m = mt*16 + l4*4 + r
#pragma unroll
  for (int mi = 0; mi < 4; ++mi) {
    int mt = wv + mi * 8;
    if (mt < 25) {
      float4 d4 = *(const float4*)(sd + mt * 16 + l4 * 4);
#pragma unroll
      for (int f = 0; f < 4; ++f) {
        short4v pk;
        pk[0] = f2bf_trunc(d4.x * acc[mi][f][0]);
        pk[1] = f2bf_trunc(d4.y * acc[mi][f][1]);
        pk[2] = f2bf_trunc(d4.z * acc[mi][f][2]);
        pk[3] = f2bf_trunc(d4.w * acc[mi][f][3]);
        *(short4v*)(y2q + (f * 16 + l15) * Y2S + mt * 16 + l4 * 4) = pk;
      }
    }
  }
  __syncthreads();

  // ---- AGG: C[m][n] = sum_k As[m][k]*y2q[n][k]; A-frags expanded in REGISTERS
  //      from LDS bitmap (broadcast b32 read). No LDS writes -> no barriers.
  f32x4 acc2[4][4];
#pragma unroll
  for (int mi = 0; mi < 4; ++mi)
#pragma unroll
    for (int f = 0; f < 4; ++f) acc2[mi][f] = (f32x4){0.f, 0.f, 0.f, 0.f};

#pragma unroll
  for (int ks = 0; ks < 13; ++ks) {
    short8 bfv[4];
#pragma unroll
    for (int f = 0; f < 4; ++f)
      bfv[f] = *(const short8*)(y2q + (f * 16 + l15) * Y2S + ks * 32 + l4 * 8);
#pragma unroll
    for (int mi = 0; mi < 4; ++mi) {
      int mt = wv + mi * 8;
      if (mt < 25) {
        unsigned int wd = bmpL[(mt * 16 + l15) * BMW + ks];
        unsigned int byt = (wd >> (l4 * 8)) & 0xFFu;
        short8 af;
#pragma unroll
        for (int e = 0; e < 8; ++e)
          af[e] = (short)(((byt >> e) & 1u) * 0x3F80u);
#pragma unroll
        for (int f = 0; f < 4; ++f)
          acc2[mi][f] = __builtin_amdgcn_mfma_f32_16x16x32_bf16(af, bfv[f], acc2[mi][f], 0, 0, 0);
      }
    }
  }

  // ---- epilogue: s(n) = sum_m relu(dis_m * C[m][n] + b2[n]); pool across waves
#pragma unroll
  for (int f = 0; f < 4; ++f) {
    float b2v = b2[q * 64 + f * 16 + l15];
    float s = 0.f;
#pragma unroll
    for (int mi = 0; mi < 4; ++mi) {
      int mt = wv + mi * 8;
      if (mt < 25) {
        float4 d4 = *(const float4*)(sd + mt * 16 + l4 * 4);
        s += fmaxf(d4.x * acc2[mi][f][0] + b2v, 0.f)
           + fmaxf(d4.y * acc2[mi][f][1] + b2v, 0.f)
           + fmaxf(d4.z * acc2[mi][f][2] + b2v, 0.f)
           + fmaxf(d4.w * acc2[mi][f][3] + b2v, 0.f);
      }
    }
    s += __shfl_xor(s, 16);
    s += __shfl_xor(s, 32);
    if (l4 == 0) pool[wv * 64 + f * 16 + l15] = s;
  }
  __syncthreads();
  if (t < 64) {
    float sum = 0.f;
#pragma unroll
    for (int w8 = 0; w8 < 8; ++w8) sum += pool[w8 * 64 + t];
    pooled[(size_t)bg * HH + q * 64 + t] = sum;
  }
}

// ---- K6: logits = (pooled/400) @ Wlin + blin. 2 graphs per block.
__global__ __launch_bounds__(256) void k_out(
    const float* __restrict__ pooled, const float* __restrict__ Wlin,
    const float* __restrict__ blin, float* __restrict__ out) {
  int bb = blockIdx.x * 2, t = threadIdx.x;
  __shared__ float ps[2][HH];
  ps[0][t] = pooled[(size_t)bb * HH + t] * (1.f / 400.f);
  ps[1][t] = pooled[(size_t)(bb + 1) * HH + t] * (1.f / 400.f);
  __syncthreads();
#pragma unroll
  for (int c = 0; c < 4; ++c) {
    int o = t + c * 256;
    if (o < OUTD) {
      float a0 = blin[o], a1 = a0;
#pragma unroll 8
      for (int h = 0; h < HH; ++h) {
        float wv = Wlin[h * OUTD + o];
        a0 += ps[0][h] * wv;
        a1 += ps[1][h] * wv;
      }
      out[(size_t)bb * OUTD + o] = a0;
      out[(size_t)(bb + 1) * OUTD + o] = a1;
    }
  }
}

extern "C" void kernel_launch(void* const* d_in, const int* in_sizes, int n_in,
                              void* d_out, int out_size, void* d_ws, size_t ws_size,
                              hipStream_t stream) {
  const float* adj   = (const float*)d_in[0];
  const float* times = (const float*)d_in[1];
  const float* W1    = (const float*)d_in[2];
  const float* b1    = (const float*)d_in[3];
  const float* W2    = (const float*)d_in[4];
  const float* b2    = (const float*)d_in[5];
  const float* Wlin  = (const float*)d_in[6];
  const float* blin  = (const float*)d_in[7];
  float* out = (float*)d_out;

  char* ws = (char*)d_ws;
  size_t off = 0;
  auto alloc = [&](size_t bytes) -> void* {
    void* ptr = ws + off;
    off = (off + bytes + 255) & ~(size_t)255;
    return ptr;
  };
  float* dis    = (float*)alloc((size_t)BATCH * NN * 4);
  float* dd     = (float*)alloc((size_t)BATCH * NN * 4);
  float* pp     = (float*)alloc((size_t)BATCH * NN * 4);
  float* qq     = (float*)alloc((size_t)BATCH * NN * 4);
  float* tproj  = (float*)alloc((size_t)BATCH * HH * 4);
  float* pooled = (float*)alloc((size_t)BATCH * HH * 4);
  short* W2Tg   = (short*)alloc((size_t)HH * W2PAD * 2);
  unsigned int* bits = (unsigned int*)alloc((size_t)BATCH * NN * BITW * 4);

  k_temb<<<BATCH, 256, 0, stream>>>(times, W1, tproj);
  k_w2t<<<HH, 256, 0, stream>>>(W2, W2Tg);
  k_prep<<<dim3(BATCH, 25), 256, 0, stream>>>(adj, bits, dis, dd);
  k_pq<<<BATCH, 512, 0, stream>>>(bits, dis, dd, pp, qq);
  k_fused<<<dim3(BATCH, 4), 512, 114688, stream>>>(
      bits, dis, pp, qq, W2Tg, W1, b1, tproj, b2, pooled);
  k_out<<<128, 256, 0, stream>>>(pooled, Wlin, blin, out);
}

// Round 8
// 161.020 us; speedup vs baseline: 2.6798x; 1.0015x over previous
//
#include <hip/hip_runtime.h>
#include <cstdint>
#include <cstddef>

#define BATCH 256
#define NN 400
#define HH 256
#define TDIM 128
#define HALFD 64
#define OUTD 800
#define BITW 16     // u32 words per bitmap row in global (13 used)
#define BMW 13
#define W2PAD 264   // W2T row stride (shorts)
#define Y2S 416     // y2 quarter LDS row stride (shorts)

using short8  = __attribute__((ext_vector_type(8))) short;
using short4v = __attribute__((ext_vector_type(4))) short;
using f32x4   = __attribute__((ext_vector_type(4))) float;

__device__ __forceinline__ short f2bf_trunc(float x) {
  union { float f; unsigned int u; } c; c.f = x; return (short)(c.u >> 16);
}
__device__ __forceinline__ short f2bf_rne(float x) {
  union { float f; unsigned int u; } c; c.f = x;
  unsigned int r = c.u + 0x7FFFu + ((c.u >> 16) & 1u);
  return (short)(r >> 16);
}

// ---- K1: adj -> bitmap [256][400][16 u32] (binary + self loop), dis, dd.
__global__ __launch_bounds__(256) void k_prep(const float* __restrict__ adj,
    unsigned int* __restrict__ bits, float* __restrict__ dis,
    float* __restrict__ dd) {
  int bg = blockIdx.x;
  int rbase = blockIdx.y * 16;
  int wv = threadIdx.x >> 6, lane = threadIdx.x & 63;
#pragma unroll
  for (int rr = 0; rr < 4; ++rr) {
    int i = rbase + wv * 4 + rr;
    const float* arow = adj + ((size_t)bg * NN + i) * NN;
    unsigned int b8 = 0; int c = 0;
    if (lane < 50) {
      float4 v0 = *(const float4*)(arow + 8 * lane);
      float4 v1 = *(const float4*)(arow + 8 * lane + 4);
      b8 = (v0.x != 0.f ? 1u : 0u) | (v0.y != 0.f ? 2u : 0u) |
           (v0.z != 0.f ? 4u : 0u) | (v0.w != 0.f ? 8u : 0u) |
           (v1.x != 0.f ? 16u : 0u) | (v1.y != 0.f ? 32u : 0u) |
           (v1.z != 0.f ? 64u : 0u) | (v1.w != 0.f ? 128u : 0u);
      c = __popc(b8);
      if ((i >> 3) == lane) b8 |= 1u << (i & 7);  // self loop
    }
    int cs = c;
#pragma unroll
    for (int s = 32; s; s >>= 1) cs += __shfl_xor(cs, s);
    unsigned int p0 = (unsigned int)__shfl((int)b8, 4 * lane);
    unsigned int p1 = (unsigned int)__shfl((int)b8, 4 * lane + 1);
    unsigned int p2 = (unsigned int)__shfl((int)b8, 4 * lane + 2);
    unsigned int p3 = (unsigned int)__shfl((int)b8, 4 * lane + 3);
    if (lane < BITW)
      bits[((size_t)bg * NN + i) * BITW + lane] =
          (lane < BMW) ? (p0 | (p1 << 8) | (p2 << 16) | (p3 << 24)) : 0u;
    if (lane == 0) {
      float d = rsqrtf((float)cs + 1.f);
      dis[bg * NN + i] = d;
      dd[bg * NN + i] = d * (float)cs;
    }
  }
}

// ---- K2: tproj[b,h] = temb(times[b]) @ W1[1:,:]
__global__ __launch_bounds__(256) void k_temb(
    const float* __restrict__ times, const float* __restrict__ W1,
    float* __restrict__ tproj) {
  int b = blockIdx.x, t = threadIdx.x;
  __shared__ float te[TDIM];
  if (t < HALFD) {
    float f = expf(-9.210340371976184f * (float)t / (float)(HALFD - 1));
    float arg = times[b] * f;
    te[t] = sinf(arg);
    te[t + HALFD] = cosf(arg);
  }
  __syncthreads();
  float acc = 0.f;
#pragma unroll 8
  for (int k = 0; k < TDIM; ++k) acc += te[k] * W1[(1 + k) * HH + t];
  tproj[b * HH + t] = acc;
}

// ---- K3: W2 -> bf16 transposed padded [256 n][264 k]
__global__ __launch_bounds__(256) void k_w2t(const float* __restrict__ W2,
                                             short* __restrict__ W2Tg) {
  int n = blockIdx.x, k = threadIdx.x;
  W2Tg[n * W2PAD + k] = f2bf_rne(W2[k * HH + n]);
}

// ---- K4: pp = dis_i*(As@dd), qq = dis_i*(As@dis) via bitmap ctz-walk.
__global__ __launch_bounds__(512) void k_pq(const unsigned int* __restrict__ bits,
    const float* __restrict__ dis, const float* __restrict__ dd,
    float* __restrict__ pp, float* __restrict__ qq) {
  int bg = blockIdx.x, t = threadIdx.x;
  __shared__ float sd[NN], su[NN];
  for (int j = t; j < NN; j += 512) { sd[j] = dis[bg * NN + j]; su[j] = dd[bg * NN + j]; }
  __syncthreads();
  if (t >= NN) return;
  const uint4* bp = (const uint4*)(bits + ((size_t)bg * NN + t) * BITW);
  uint4 qa = bp[0], qb = bp[1], qc = bp[2];
  unsigned int wr[13] = {qa.x, qa.y, qa.z, qa.w, qb.x, qb.y, qb.z, qb.w,
                         qc.x, qc.y, qc.z, qc.w, ((const unsigned int*)bp)[12]};
  float ps = 0.f, qs = 0.f;
#pragma unroll
  for (int w = 0; w < BMW; ++w) {
    unsigned int u = wr[w];
    int base = w * 32;
    while (u) {
      int j = base + __builtin_ctz(u);
      u &= u - 1;
      ps += su[j]; qs += sd[j];
    }
  }
  float d = sd[t];
  pp[bg * NN + t] = d * ps;
  qq[bg * NN + t] = d * qs;
}

// ---- K5: fused per-(graph, n-quarter): GEMM1(y2 quarter in LDS) ->
//      AGG (register-expanded bitmap A-frags, barrier-free K-loop) ->
//      relu -> pool. 512 thr, 8 waves, 3 barriers total.
__global__ __launch_bounds__(512, 2) void k_fused(
    const unsigned int* __restrict__ bits, const float* __restrict__ disg,
    const float* __restrict__ ppg, const float* __restrict__ qqg,
    const short* __restrict__ W2Tg, const float* __restrict__ W1,
    const float* __restrict__ b1, const float* __restrict__ tproj,
    const float* __restrict__ b2, float* __restrict__ pooled) {
  extern __shared__ char smem[];
  short* w2tq        = (short*)smem;                    // 64*264*2 = 33792
  short* y2q         = (short*)(smem + 33792);          // 64*416*2 = 53248 -> 87040
  unsigned int* bmpL = (unsigned int*)(smem + 87040);   // 400*13*4 = 20800 -> 107840
  float* sd          = (float*)(smem + 107840);         // 1600 -> 109440
  float* ppL         = (float*)(smem + 109440);         // 1600 -> 111040
  float* qqL         = (float*)(smem + 111040);         // 1600 -> 112640
  float* pool        = (float*)(smem + 112640);         // 8*64*4 = 2048 -> 114688

  int t = threadIdx.x;
  int wv = t >> 6, lane = t & 63, l15 = lane & 15, l4 = lane >> 4;
  int bg = blockIdx.x, q = blockIdx.y;

  // ---- stage: W2T quarter, bitmap, dis/pp/qq, zero y2q pad (m=400..415)
#pragma unroll
  for (int i = 0; i < 5; ++i) {
    int idx = i * 512 + t;
    if (idx < 2112) {  // 64 rows * 33 short8 chunks
      int n = idx / 33, c = idx % 33;
      *(short8*)(w2tq + n * W2PAD + c * 8) =
          *(const short8*)(W2Tg + (size_t)(q * 64 + n) * W2PAD + c * 8);
    }
  }
  if (t < NN) {
    const uint4* bp = (const uint4*)(bits + ((size_t)bg * NN + t) * BITW);
    uint4 qa = bp[0], qb = bp[1], qc = bp[2];
    bmpL[t * BMW + 0] = qa.x;  bmpL[t * BMW + 1] = qa.y;
    bmpL[t * BMW + 2] = qa.z;  bmpL[t * BMW + 3] = qa.w;
    bmpL[t * BMW + 4] = qb.x;  bmpL[t * BMW + 5] = qb.y;
    bmpL[t * BMW + 6] = qb.z;  bmpL[t * BMW + 7] = qb.w;
    bmpL[t * BMW + 8] = qc.x;  bmpL[t * BMW + 9] = qc.y;
    bmpL[t * BMW + 10] = qc.z; bmpL[t * BMW + 11] = qc.w;
    bmpL[t * BMW + 12] = ((const unsigned int*)bp)[12];
    sd[t] = disg[bg * NN + t];
    ppL[t] = ppg[bg * NN + t];
    qqL[t] = qqg[bg * NN + t];
  }
  if (t < 128) {  // zero y2q pad cols m=400..415 for all 64 n-rows
    int n = t >> 1, c = t & 1;
    short8 z = {};
    *(short8*)(y2q + n * Y2S + 400 + c * 8) = z;
  }
  __syncthreads();

  // ---- GEMM1: y2q[n][m] = dis_m * (g1 @ W2)[m][q*64+n]; k0 outer, mt inner
  const float* tpr = tproj + bg * HH;
  float pv[4], qv[4];
#pragma unroll
  for (int mi = 0; mi < 4; ++mi) {
    int mt = wv + mi * 8;
    int arow = mt * 16 + l15;
    pv[mi] = (mt < 25) ? ppL[arow] : 0.f;
    qv[mi] = (mt < 25) ? qqL[arow] : 0.f;
  }
  f32x4 acc[4][4];
#pragma unroll
  for (int mi = 0; mi < 4; ++mi)
#pragma unroll
    for (int f = 0; f < 4; ++f) acc[mi][f] = (f32x4){0.f, 0.f, 0.f, 0.f};

#pragma unroll
  for (int k0 = 0; k0 < 8; ++k0) {
    int kk = k0 * 32 + l4 * 8;
    float4 w1a = *(const float4*)(W1 + kk), w1b = *(const float4*)(W1 + kk + 4);
    float4 b1a = *(const float4*)(b1 + kk), b1b = *(const float4*)(b1 + kk + 4);
    float4 tpa = *(const float4*)(tpr + kk), tpb = *(const float4*)(tpr + kk + 4);
    short8 bf[4];
#pragma unroll
    for (int f = 0; f < 4; ++f)
      bf[f] = *(const short8*)(w2tq + (f * 16 + l15) * W2PAD + kk);
#pragma unroll
    for (int mi = 0; mi < 4; ++mi) {
      if (wv + mi * 8 < 25) {
        float ppv = pv[mi], qqv = qv[mi];
        short8 af;
        af[0] = f2bf_trunc(fmaxf(ppv * w1a.x + qqv * tpa.x + b1a.x, 0.f));
        af[1] = f2bf_trunc(fmaxf(ppv * w1a.y + qqv * tpa.y + b1a.y, 0.f));
        af[2] = f2bf_trunc(fmaxf(ppv * w1a.z + qqv * tpa.z + b1a.z, 0.f));
        af[3] = f2bf_trunc(fmaxf(ppv * w1a.w + qqv * tpa.w + b1a.w, 0.f));
        af[4] = f2bf_trunc(fmaxf(ppv * w1b.x + qqv * tpb.x + b1b.x, 0.f));
        af[5] = f2bf_trunc(fmaxf(ppv * w1b.y + qqv * tpb.y + b1b.y, 0.f));
        af[6] = f2bf_trunc(fmaxf(ppv * w1b.z + qqv * tpb.z + b1b.z, 0.f));
        af[7] = f2bf_trunc(fmaxf(ppv * w1b.w + qqv * tpb.w + b1b.w, 0.f));
#pragma unroll
        for (int f = 0; f < 4; ++f)
          acc[mi][f] = __builtin_amdgcn_mfma_f32_16x16x32_bf16(af, bf[f], acc[mi][f], 0, 0, 0);
      }
    }
  }
  // write y2q (transposed, dis-scaled): n = f*16+l15, m = mt*16 + l4*4 + r
#pragma unroll
  for (int mi = 0; mi < 4; ++mi) {
    int mt = wv + mi * 8;
    if (mt < 25) {
      float4 d4 = *(const float4*)(sd + mt * 16 + l4 * 4);
#pragma unroll
      for (int f = 0; f < 4; ++f) {
        short4v pk;
        pk[0] = f2bf_trunc(d4.x * acc[mi][f][0]);
        pk[1] = f2bf_trunc(d4.y * acc[mi][f][1]);
        pk[2] = f2bf_trunc(d4.z * acc[mi][f][2]);
        pk[3] = f2bf_trunc(d4.w * acc[mi][f][3]);
        *(short4v*)(y2q + (f * 16 + l15) * Y2S + mt * 16 + l4 * 4) = pk;
      }
    }
  }
  __syncthreads();

  // ---- AGG: C[m][n] = sum_k As[m][k]*y2q[n][k]; A-frags expanded in REGISTERS
  //      from LDS bitmap (broadcast b32 read). No LDS writes -> no barriers.
  f32x4 acc2[4][4];
#pragma unroll
  for (int mi = 0; mi < 4; ++mi)
#pragma unroll
    for (int f = 0; f < 4; ++f) acc2[mi][f] = (f32x4){0.f, 0.f, 0.f, 0.f};

#pragma unroll
  for (int ks = 0; ks < 13; ++ks) {
    short8 bfv[4];
#pragma unroll
    for (int f = 0; f < 4; ++f)
      bfv[f] = *(const short8*)(y2q + (f * 16 + l15) * Y2S + ks * 32 + l4 * 8);
#pragma unroll
    for (int mi = 0; mi < 4; ++mi) {
      int mt = wv + mi * 8;
      if (mt < 25) {
        unsigned int wd = bmpL[(mt * 16 + l15) * BMW + ks];
        unsigned int byt = (wd >> (l4 * 8)) & 0xFFu;
        short8 af;
#pragma unroll
        for (int e = 0; e < 8; ++e)
          af[e] = (short)(((byt >> e) & 1u) * 0x3F80u);
#pragma unroll
        for (int f = 0; f < 4; ++f)
          acc2[mi][f] = __builtin_amdgcn_mfma_f32_16x16x32_bf16(af, bfv[f], acc2[mi][f], 0, 0, 0);
      }
    }
  }

  // ---- epilogue: s(n) = sum_m relu(dis_m * C[m][n] + b2[n]); pool across waves
#pragma unroll
  for (int f = 0; f < 4; ++f) {
    float b2v = b2[q * 64 + f * 16 + l15];
    float s = 0.f;
#pragma unroll
    for (int mi = 0; mi < 4; ++mi) {
      int mt = wv + mi * 8;
      if (mt < 25) {
        float4 d4 = *(const float4*)(sd + mt * 16 + l4 * 4);
        s += fmaxf(d4.x * acc2[mi][f][0] + b2v, 0.f)
           + fmaxf(d4.y * acc2[mi][f][1] + b2v, 0.f)
           + fmaxf(d4.z * acc2[mi][f][2] + b2v, 0.f)
           + fmaxf(d4.w * acc2[mi][f][3] + b2v, 0.f);
      }
    }
    s += __shfl_xor(s, 16);
    s += __shfl_xor(s, 32);
    if (l4 == 0) pool[wv * 64 + f * 16 + l15] = s;
  }
  __syncthreads();
  if (t < 64) {
    float sum = 0.f;
#pragma unroll
    for (int w8 = 0; w8 < 8; ++w8) sum += pool[w8 * 64 + t];
    pooled[(size_t)bg * HH + q * 64 + t] = sum;
  }
}

// ---- K6: logits = (pooled/400) @ Wlin + blin. 2 graphs per block.
__global__ __launch_bounds__(256) void k_out(
    const float* __restrict__ pooled, const float* __restrict__ Wlin,
    const float* __restrict__ blin, float* __restrict__ out) {
  int bb = blockIdx.x * 2, t = threadIdx.x;
  __shared__ float ps[2][HH];
  ps[0][t] = pooled[(size_t)bb * HH + t] * (1.f / 400.f);
  ps[1][t] = pooled[(size_t)(bb + 1) * HH + t] * (1.f / 400.f);
  __syncthreads();
#pragma unroll
  for (int c = 0; c < 4; ++c) {
    int o = t + c * 256;
    if (o < OUTD) {
      float a0 = blin[o], a1 = a0;
#pragma unroll 8
      for (int h = 0; h < HH; ++h) {
        float wv = Wlin[h * OUTD + o];
        a0 += ps[0][h] * wv;
        a1 += ps[1][h] * wv;
      }
      out[(size_t)bb * OUTD + o] = a0;
      out[(size_t)(bb + 1) * OUTD + o] = a1;
    }
  }
}

extern "C" void kernel_launch(void* const* d_in, const int* in_sizes, int n_in,
                              void* d_out, int out_size, void* d_ws, size_t ws_size,
                              hipStream_t stream) {
  const float* adj   = (const float*)d_in[0];
  const float* times = (const float*)d_in[1];
  const float* W1    = (const float*)d_in[2];
  const float* b1    = (const float*)d_in[3];
  const float* W2    = (const float*)d_in[4];
  const float* b2    = (const float*)d_in[5];
  const float* Wlin  = (const float*)d_in[6];
  const float* blin  = (const float*)d_in[7];
  float* out = (float*)d_out;

  char* ws = (char*)d_ws;
  size_t off = 0;
  auto alloc = [&](size_t bytes) -> void* {
    void* ptr = ws + off;
    off = (off + bytes + 255) & ~(size_t)255;
    return ptr;
  };
  float* dis    = (float*)alloc((size_t)BATCH * NN * 4);
  float* dd     = (float*)alloc((size_t)BATCH * NN * 4);
  float* pp     = (float*)alloc((size_t)BATCH * NN * 4);
  float* qq     = (float*)alloc((size_t)BATCH * NN * 4);
  float* tproj  = (float*)alloc((size_t)BATCH * HH * 4);
  float* pooled = (float*)alloc((size_t)BATCH * HH * 4);
  short* W2Tg   = (short*)alloc((size_t)HH * W2PAD * 2);
  unsigned int* bits = (unsigned int*)alloc((size_t)BATCH * NN * BITW * 4);

  k_temb<<<BATCH, 256, 0, stream>>>(times, W1, tproj);
  k_w2t<<<HH, 256, 0, stream>>>(W2, W2Tg);
  k_prep<<<dim3(BATCH, 25), 256, 0, stream>>>(adj, bits, dis, dd);
  k_pq<<<BATCH, 512, 0, stream>>>(bits, dis, dd, pp, qq);
  k_fused<<<dim3(BATCH, 4), 512, 114688, stream>>>(
      bits, dis, pp, qq, W2Tg, W1, b1, tproj, b2, pooled);
  k_out<<<128, 256, 0, stream>>>(pooled, Wlin, blin, out);
}